// Round 8
// baseline (2486.213 us; speedup 1.0000x reference)
//
#include <hip/hip_runtime.h>
#include <hip/hip_bf16.h>

#define H 1024
#define NS 32
#define SS 256
#define T_Q 16384            /* query tokens  (64 x 256) */
#define M_S 8192             /* support tokens (32 x 256) */

typedef __hip_bfloat16 bf16;
typedef short short8 __attribute__((ext_vector_type(8)));
typedef float floatx4 __attribute__((ext_vector_type(4)));
typedef float floatx16 __attribute__((ext_vector_type(16)));

__device__ __forceinline__ float ldf(const bf16& v) { return __bfloat162float(v); }

// two-term bf16 split: v ~= hi + lo  (residual ~2^-16 relative)
__device__ __forceinline__ void split2(float v, bf16& h, bf16& l) {
  h = __float2bfloat16(v);
  l = __float2bfloat16(v - __bfloat162float(h));
}

// async global->LDS, 16B per lane; LDS dest = wave-uniform base + lane*16
__device__ __forceinline__ void gl2lds16(const void* g, void* l) {
  __builtin_amdgcn_global_load_lds(
      (const __attribute__((address_space(1))) unsigned int*)g,
      (__attribute__((address_space(3))) unsigned int*)l, 16, 0, 0);
}

__device__ __forceinline__ short8 ld8s(const bf16* p) { return *(const short8*)p; }

// ---------------- fp32 -> bf16 hi/lo split convert ----------------
__global__ __launch_bounds__(256) void conv_split(const float* __restrict__ in,
                                                  bf16* __restrict__ oh,
                                                  bf16* __restrict__ ol, int n)
{
  int i = blockIdx.x * 256 + threadIdx.x;
  if (i < n) { bf16 h, l; split2(in[i], h, l); oh[i] = h; ol[i] = l; }
}

// -------- transpose + split: Wh/Wl[n][k] = split(W[k][n]).  grid (N/32, K/32) --------
__global__ __launch_bounds__(256) void transpose_split(
    const float* __restrict__ W, bf16* __restrict__ Wh, bf16* __restrict__ Wl,
    int K, int N)
{
  __shared__ float t[32][33];
  int n0 = blockIdx.x * 32, k0 = blockIdx.y * 32;
  int tx = threadIdx.x & 31, ty = threadIdx.x >> 5;
#pragma unroll
  for (int i = 0; i < 32; i += 8)
    t[ty + i][tx] = W[(size_t)(k0 + ty + i) * N + (n0 + tx)];
  __syncthreads();
#pragma unroll
  for (int i = 0; i < 32; i += 8) {
    bf16 h, l; split2(t[tx][ty + i], h, l);
    size_t o = (size_t)(n0 + ty + i) * K + (k0 + tx);
    Wh[o] = h;
    if (Wl) Wl[o] = l;
  }
}

// ------- split-bf16 MFMA GEMM, v8: v7 (32x32x16) with the beta-read race FIXED -------
// C = act( [A0|A1] @ Wt^T + bias ), as Ah@Wh + Al@Wh (+ Ah@Wl).
// BM=256 BN=256 BK=32, 512 thr = 8 waves (2M x 4N), per-wave 128x64 out as
// 4 at-tiles(32 rows) x 2 bt-tiles(32 cols) of mfma_f32_32x32x16_bf16.
// 16-row fragment-major LDS staging (per-lane SOURCE permutation, linear dest,
// 0 conflicts); a 32x32 fragment spans two 16-row tiles via
//   fb = ((l&31)>>4)*512 + (l>>5)*128 + (l&15)*8   (elems).
// RACE FIX vs v7: pre-barrier P3 reads touch ONLY alpha-staged tiles (B frags +
// at0) — collectively gated by end-P2 vmcnt(3)+barrier. The at1 fragment (beta-
// staged tiles) is read at the TOP of next P0, i.e. after the end-P3 barrier
// made everyone's beta-vmcnt(0) collective. (vmcnt is per-wave; v7 read other
// waves' beta tiles pre-barrier.)
template<bool RELU, bool HASWL>
__global__ __launch_bounds__(512, 2) void gemm3p(
    const bf16* __restrict__ A0h, const bf16* __restrict__ A0l,
    const bf16* __restrict__ A1h, const bf16* __restrict__ A1l,
    const bf16* __restrict__ Wh,  const bf16* __restrict__ Wl,
    const float* __restrict__ bias,
    bf16* __restrict__ Ch, bf16* __restrict__ Cl,
    int M, int N, int K0, int Ktot)
{
  (void)M;
  // per-buffer (32768 bf16 = 64KB): Ah[16 tiles]|Al[16]|Bh[16]|Bl[16], tile=512 bf16
  __shared__ __align__(16) bf16 lds[2 * 32768];   // 128 KB
  const int tid = threadIdx.x;
  const int w = tid >> 6, l = tid & 63;
  // bijective XCD swizzle: xcd pair -> one bn column panel
  const int nbm = gridDim.x >> 2;
  const int lid = blockIdx.x;
  const int xcd = lid & 7, ib = lid >> 3;
  const int half = nbm >> 1;
  const int bn = xcd >> 1;
  const int bm = (xcd & 1) * half + ib;
  const int wr = w >> 2, wn = w & 3;              // wave row 0..1, col 0..3
  const int srow = l & 15;                        // staging source row in tile
  const int scol = (l >> 4) * 8;                  // staging source k-offset
  // 32x32 fragment per-lane offset within a tile-pair (elems)
  const int fb = (((l & 31) >> 4) << 9) + ((l >> 5) << 7) + ((l & 15) << 3);

  floatx16 acc[4][2];
#pragma unroll
  for (int i = 0; i < 4; i++)
#pragma unroll
    for (int j = 0; j < 2; j++)
#pragma unroll
      for (int r = 0; r < 16; r++) acc[i][j][r] = 0.f;

  // ---- staging assignment (identical to v6) ----
  // alpha: B tiles {2w, 2w+1} h(+l)  +  one A load: tile {0,1,8,9}[w>>1], part w&1
  const size_t raB0 = (size_t)(bn * 256 + (2 * w)     * 16 + srow) * Ktot + scol;
  const size_t raB1 = (size_t)(bn * 256 + (2 * w + 1) * 16 + srow) * Ktot + scol;
  const int aT  = ((w >> 1) & 1) + ((w >> 1) >> 1) * 8;   // {0,1,8,9}
  const int aLo = w & 1;
  const size_t raA = (size_t)(bm * 256 + aT * 16 + srow) * H + scol;
  const int aDst = (aLo ? 8192 : 0) + aT * 512;
  // beta: 24 A loads over tiles {2..7,10..15} x {h,l}; wave w takes j = 3w..3w+2
  size_t raBt[3]; int bDst[3]; int bLo[3];
#pragma unroll
  for (int i = 0; i < 3; i++) {
    int j = w * 3 + i;
    int idx = j >> 1;
    int tb = (idx < 6) ? (idx + 2) : (idx + 4);           // {2..7,10..15}
    bLo[i] = j & 1;
    raBt[i] = (size_t)(bm * 256 + tb * 16 + srow) * H + scol;
    bDst[i] = (bLo[i] ? 8192 : 0) + tb * 512;
  }

  auto stage_alpha = [&](int t) {
    const int k0 = t << 5;
    const bf16 *Ah_, *Al_; int ke;
    if (k0 < K0) { Ah_ = A0h; Al_ = A0l; ke = k0; }
    else         { Ah_ = A1h; Al_ = A1l; ke = k0 - K0; }
    bf16* buf = lds + (t & 1) * 32768;
    gl2lds16(Wh + raB0 + k0, buf + 16384 + (2 * w) * 512);
    gl2lds16(Wh + raB1 + k0, buf + 16384 + (2 * w + 1) * 512);
    if (HASWL) {
      gl2lds16(Wl + raB0 + k0, buf + 24576 + (2 * w) * 512);
      gl2lds16(Wl + raB1 + k0, buf + 24576 + (2 * w + 1) * 512);
    }
    gl2lds16((aLo ? Al_ : Ah_) + raA + ke, buf + aDst);
  };
  auto stage_beta = [&](int t) {
    const int k0 = t << 5;
    const bf16 *Ah_, *Al_; int ke;
    if (k0 < K0) { Ah_ = A0h; Al_ = A0l; ke = k0; }
    else         { Ah_ = A1h; Al_ = A1l; ke = k0 - K0; }
    bf16* buf = lds + (t & 1) * 32768;
#pragma unroll
    for (int i = 0; i < 3; i++)
      gl2lds16((bLo[i] ? Al_ : Ah_) + raBt[i] + ke, buf + bDst[i]);
  };

  // prologue: stage step 0, drain (prologue only), pre-read step-0 operands
  stage_alpha(0);
  stage_beta(0);
  asm volatile("s_waitcnt vmcnt(0)" ::: "memory");
  __builtin_amdgcn_s_barrier();

  // B frags for current step: (bt, kh) x (h,l); static names (rule #20)
  short8 Bh0[2], Bh1[2], Bl0[2], Bl1[2];
  short8 s0h[2], s0l[2], s1h[2], s1l[2];  // A frag ping-pong (2 at-tiles per set)
  {
    const bf16* pB = lds + 16384 + wn * 2048 + fb;
    Bh0[0] = ld8s(pB);         Bh0[1] = ld8s(pB + 1024);
    Bh1[0] = ld8s(pB + 256);   Bh1[1] = ld8s(pB + 1024 + 256);
    if (HASWL) {
      Bl0[0] = ld8s(pB + 8192);        Bl0[1] = ld8s(pB + 8192 + 1024);
      Bl1[0] = ld8s(pB + 8192 + 256);  Bl1[1] = ld8s(pB + 8192 + 1024 + 256);
    }
    const bf16* pA = lds + wr * 4096 + fb;
    s0h[0] = ld8s(pA);         s0l[0] = ld8s(pA + 8192);
  }

  const int nT = Ktot >> 5;

#define MM32(AT, BT, BH, BL, AH, AL)                                                               \
    acc[AT][BT] = __builtin_amdgcn_mfma_f32_32x32x16_bf16(AH, BH, acc[AT][BT], 0, 0, 0);           \
    acc[AT][BT] = __builtin_amdgcn_mfma_f32_32x32x16_bf16(AL, BH, acc[AT][BT], 0, 0, 0);           \
    if (HASWL)                                                                                     \
      acc[AT][BT] = __builtin_amdgcn_mfma_f32_32x32x16_bf16(AH, BL, acc[AT][BT], 0, 0, 0);

  for (int t = 0; t < nT; ++t) {
    const bf16* buf  = lds + (t & 1) * 32768;
    const bf16* nbuf = lds + ((t + 1) & 1) * 32768;
    const bf16* pA   = buf + wr * 4096 + fb;
    const bf16* pAl  = pA + 8192;

    // ---- P0: read at1 kh0 (beta tiles, now collectively gated by the barrier);
    //          issue alpha(t+1); read S1 = at{2,3} kh0; MFMA at{0,1} kh0 ----
    s0h[1] = ld8s(pA + 1024);   s0l[1] = ld8s(pAl + 1024);
    if (t + 1 < nT) stage_alpha(t + 1);
    s1h[0] = ld8s(pA + 2048);   s1h[1] = ld8s(pA + 3072);
    s1l[0] = ld8s(pAl + 2048);  s1l[1] = ld8s(pAl + 3072);
    __builtin_amdgcn_s_setprio(1);
    MM32(0, 0, Bh0[0], Bl0[0], s0h[0], s0l[0])
    MM32(0, 1, Bh0[1], Bl0[1], s0h[0], s0l[0])
    MM32(1, 0, Bh0[0], Bl0[0], s0h[1], s0l[1])
    MM32(1, 1, Bh0[1], Bl0[1], s0h[1], s0l[1])
    __builtin_amdgcn_s_setprio(0);
    // (no barrier: buf is read-only this step)

    // ---- P1: issue beta(t+1); read S0 = at{0,1} kh1; MFMA at{2,3} kh0 (S1) ----
    if (t + 1 < nT) stage_beta(t + 1);
    s0h[0] = ld8s(pA + 256);          s0h[1] = ld8s(pA + 1024 + 256);
    s0l[0] = ld8s(pAl + 256);         s0l[1] = ld8s(pAl + 1024 + 256);
    __builtin_amdgcn_s_setprio(1);
    MM32(2, 0, Bh0[0], Bl0[0], s1h[0], s1l[0])
    MM32(2, 1, Bh0[1], Bl0[1], s1h[0], s1l[0])
    MM32(3, 0, Bh0[0], Bl0[0], s1h[1], s1l[1])
    MM32(3, 1, Bh0[1], Bl0[1], s1h[1], s1l[1])
    __builtin_amdgcn_s_setprio(0);
    // (no barrier)

    // ---- P2: read S1 = at{2,3} kh1; MFMA at{0,1} kh1 (S0); gate alpha(t+1) ----
    s1h[0] = ld8s(pA + 2048 + 256);   s1h[1] = ld8s(pA + 3072 + 256);
    s1l[0] = ld8s(pAl + 2048 + 256);  s1l[1] = ld8s(pAl + 3072 + 256);
    __builtin_amdgcn_s_setprio(1);
    MM32(0, 0, Bh1[0], Bl1[0], s0h[0], s0l[0])
    MM32(0, 1, Bh1[1], Bl1[1], s0h[0], s0l[0])
    MM32(1, 0, Bh1[0], Bl1[0], s0h[1], s0l[1])
    MM32(1, 1, Bh1[1], Bl1[1], s0h[1], s0l[1])
    __builtin_amdgcn_s_setprio(0);
    if (t + 1 < nT) asm volatile("s_waitcnt vmcnt(3)" ::: "memory");
    __builtin_amdgcn_s_barrier();

    // ---- P3: MFMA at{2,3} kh1 (S1); pre-read next-step ALPHA-staged data only
    //          (B frags + at0); gate own beta; barrier makes it collective ----
    __builtin_amdgcn_s_setprio(1);
    MM32(2, 0, Bh1[0], Bl1[0], s1h[0], s1l[0])
    MM32(2, 1, Bh1[1], Bl1[1], s1h[0], s1l[0])
    MM32(3, 0, Bh1[0], Bl1[0], s1h[1], s1l[1])
    MM32(3, 1, Bh1[1], Bl1[1], s1h[1], s1l[1])
    __builtin_amdgcn_s_setprio(0);
    if (t + 1 < nT) {
      const bf16* nB = nbuf + 16384 + wn * 2048 + fb;
      const bf16* nA = nbuf + wr * 4096 + fb;
      Bh0[0] = ld8s(nB);         Bh0[1] = ld8s(nB + 1024);
      Bh1[0] = ld8s(nB + 256);   Bh1[1] = ld8s(nB + 1024 + 256);
      if (HASWL) {
        Bl0[0] = ld8s(nB + 8192);        Bl0[1] = ld8s(nB + 8192 + 1024);
        Bl1[0] = ld8s(nB + 8192 + 256);  Bl1[1] = ld8s(nB + 8192 + 1024 + 256);
      }
      s0h[0] = ld8s(nA);         s0l[0] = ld8s(nA + 8192);
      asm volatile("s_waitcnt vmcnt(0)" ::: "memory");  // own beta(t+1) drained
    }
    __builtin_amdgcn_s_barrier();                       // -> collective: all beta landed
  }
#undef MM32

  // epilogue: 32x32 C/D layout col=lane&31, row=(r&3)+8*(r>>2)+4*(lane>>5)
#pragma unroll
  for (int at = 0; at < 4; at++) {
#pragma unroll
    for (int bt = 0; bt < 2; bt++) {
      int col  = bn * 256 + wn * 64 + bt * 32 + (l & 31);
      int row0 = bm * 256 + wr * 128 + at * 32 + 4 * (l >> 5);
      float bv = bias ? bias[col] : 0.f;
#pragma unroll
      for (int r = 0; r < 16; r++) {
        int row = row0 + (r & 3) + 8 * (r >> 2);
        float v = acc[at][bt][r] + bv;
        if (RELU) v = fmaxf(v, 0.f);
        bf16 h, lo; split2(v, h, lo);
        size_t o = (size_t)row * N + col;
        Ch[o] = h; Cl[o] = lo;
      }
    }
  }
}

// ---------------- LayerNorm on hi/lo pair (fp32 stats), in place ----------------
__global__ __launch_bounds__(256) void ln_pair(
    bf16* __restrict__ hh, bf16* __restrict__ hl,
    const float* __restrict__ g, const float* __restrict__ be)
{
  int row = blockIdx.x;
  bf16* ph = hh + (size_t)row * H;
  bf16* pl = hl + (size_t)row * H;
  int tid = threadIdx.x;
  float v[4];
  float s = 0.f, sq = 0.f;
#pragma unroll
  for (int j = 0; j < 4; j++) {
    int hi = tid + 256 * j;
    v[j] = ldf(ph[hi]) + ldf(pl[hi]);
    s += v[j]; sq += v[j] * v[j];
  }
  __shared__ float rs[256], rq[256];
  rs[tid] = s; rq[tid] = sq; __syncthreads();
  for (int o = 128; o; o >>= 1) {
    if (tid < o) { rs[tid] += rs[tid + o]; rq[tid] += rq[tid + o]; }
    __syncthreads();
  }
  float mu   = rs[0] * (1.0f / H);
  float var  = rq[0] * (1.0f / H) - mu * mu;
  float rstd = rsqrtf(var + 1e-5f);
#pragma unroll
  for (int j = 0; j < 4; j++) {
    int hi = tid + 256 * j;
    bf16 h, l; split2(g[hi] * (v[j] - mu) * rstd + be[hi], h, l);
    ph[hi] = h; pl[hi] = l;
  }
}

// ------------- per-sentence masked-mean prototypes (pair in, fp32 out) -------------
__global__ __launch_bounds__(256) void proto_kernel(
    const bf16* __restrict__ eh, const bf16* __restrict__ el,
    const int* __restrict__ labels, float* __restrict__ protos_out)
{
  int p = blockIdx.x;
  int tid = threadIdx.x;
  __shared__ unsigned char lbl[SS];
  lbl[tid] = (labels[p * SS + tid] > 0) ? 1 : 0;
  __syncthreads();
  float acc[4] = {0.f, 0.f, 0.f, 0.f};
  int cnt = 0;
  const bf16* bh = eh + (size_t)p * SS * H;
  const bf16* bl = el + (size_t)p * SS * H;
  for (int s = 0; s < SS; s++) {
    if (lbl[s]) {
      cnt++;
      const bf16* rh = bh + (size_t)s * H;
      const bf16* rl = bl + (size_t)s * H;
#pragma unroll
      for (int j = 0; j < 4; j++)
        acc[j] += ldf(rh[tid + 256 * j]) + ldf(rl[tid + 256 * j]);
    }
  }
  float ic = 1.0f / fmaxf((float)cnt, 1.0f);
#pragma unroll
  for (int j = 0; j < 4; j++) protos_out[p * H + tid + 256 * j] = acc[j] * ic;
}

// ---------------- normalize prototypes -> pn bf16 hi/lo pair ----------------
__global__ __launch_bounds__(256) void pn_kernel(
    const float* __restrict__ protos, bf16* __restrict__ pnh, bf16* __restrict__ pnl)
{
  int p = blockIdx.x;
  int tid = threadIdx.x;
  __shared__ float red[256];
  float v[4];
  float sq = 0.f;
#pragma unroll
  for (int j = 0; j < 4; j++) { v[j] = protos[p * H + tid + 256 * j]; sq += v[j] * v[j]; }
  red[tid] = sq; __syncthreads();
  for (int o = 128; o; o >>= 1) {
    if (tid < o) red[tid] += red[tid + o];
    __syncthreads();
  }
  float inv = 1.0f / fmaxf(sqrtf(red[0]), 1e-8f);
#pragma unroll
  for (int j = 0; j < 4; j++) {
    bf16 h, l; split2(v[j] * inv, h, l);
    pnh[p * H + tid + 256 * j] = h;
    pnl[p * H + tid + 256 * j] = l;
  }
}

// ---------------- rownorm: rn[row] = 1/max(||h+l||, 1e-8) ----------------
__global__ __launch_bounds__(256) void rownorm_pair(
    const bf16* __restrict__ hh, const bf16* __restrict__ hl, float* __restrict__ rn)
{
  int row = blockIdx.x;
  int tid = threadIdx.x;
  const bf16* ph = hh + (size_t)row * H;
  const bf16* pl = hl + (size_t)row * H;
  float s = 0.f;
#pragma unroll
  for (int j = 0; j < 4; j++) {
    float v = ldf(ph[tid + 256 * j]) + ldf(pl[tid + 256 * j]);
    s += v * v;
  }
  __shared__ float rs[256];
  rs[tid] = s; __syncthreads();
  for (int o = 128; o; o >>= 1) {
    if (tid < o) rs[tid] += rs[tid + o];
    __syncthreads();
  }
  if (tid == 0) rn[row] = 1.0f / fmaxf(sqrtf(rs[0]), 1e-8f);
}

// ---------------- sims = A_pair @ pn_pair^T  (split-3 MFMA, N=32) ----------------
// M-tile 64, 4 waves (wave w owns rows w*16..w*16+15), K=1024, BK=32.
__global__ __launch_bounds__(256) void sims_mfma(
    const bf16* __restrict__ Ah, const bf16* __restrict__ Al,
    const bf16* __restrict__ Bh, const bf16* __restrict__ Bl,
    float* __restrict__ sims)
{
  __shared__ bf16 AsH[64 * 32];
  __shared__ bf16 AsL[64 * 32];
  __shared__ bf16 BsH[32 * 32];
  __shared__ bf16 BsL[32 * 32];
  const int tid = threadIdx.x;
  const int w = tid >> 6, l = tid & 63;
  const int bm0 = blockIdx.x * 64;
  const int m16 = l & 15, quad = l >> 4;
  const int sr = l >> 2;           // staging row within wave segment
  const int sc = (l & 3) * 8;      // staging k-offset

  floatx4 acc[2];
#pragma unroll
  for (int nt = 0; nt < 2; nt++) { acc[nt][0]=0.f; acc[nt][1]=0.f; acc[nt][2]=0.f; acc[nt][3]=0.f; }

  for (int k0 = 0; k0 < H; k0 += 32) {
    gl2lds16(Ah + (size_t)(bm0 + w * 16 + sr) * H + k0 + sc, &AsH[w * 512]);
    gl2lds16(Al + (size_t)(bm0 + w * 16 + sr) * H + k0 + sc, &AsL[w * 512]);
    if (w < 2) gl2lds16(Bh + (size_t)(w * 16 + sr) * H + k0 + sc, &BsH[w * 512]);
    else       gl2lds16(Bl + (size_t)((w - 2) * 16 + sr) * H + k0 + sc, &BsL[(w - 2) * 512]);
    __syncthreads();

    short8 ah  = *(const short8*)&AsH[(w * 16 + m16) * 32 + quad * 8];
    short8 al8 = *(const short8*)&AsL[(w * 16 + m16) * 32 + quad * 8];
#pragma unroll
    for (int nt = 0; nt < 2; nt++) {
      short8 bh  = *(const short8*)&BsH[(nt * 16 + m16) * 32 + quad * 8];
      short8 bl8 = *(const short8*)&BsL[(nt * 16 + m16) * 32 + quad * 8];
      acc[nt] = __builtin_amdgcn_mfma_f32_16x16x32_bf16(ah,  bh,  acc[nt], 0, 0, 0);
      acc[nt] = __builtin_amdgcn_mfma_f32_16x16x32_bf16(al8, bh,  acc[nt], 0, 0, 0);
      acc[nt] = __builtin_amdgcn_mfma_f32_16x16x32_bf16(ah,  bl8, acc[nt], 0, 0, 0);
    }
    __syncthreads();
  }

#pragma unroll
  for (int nt = 0; nt < 2; nt++) {
    int col  = nt * 16 + m16;
    int row0 = bm0 + w * 16 + quad * 4;
#pragma unroll
    for (int r = 0; r < 4; r++)
      sims[(size_t)(row0 + r) * 32 + col] = acc[nt][r];
  }
}

// ---------------- softmax over 32 protos; half-wave per token ----------------
__global__ __launch_bounds__(256) void softmax32(
    const float* __restrict__ sims, const float* __restrict__ rn,
    float* __restrict__ wts)
{
  int t = blockIdx.x * 8 + (threadIdx.x >> 5);
  int p = threadIdx.x & 31;
  float s = sims[(size_t)t * 32 + p] * rn[t];
  float m = s;
#pragma unroll
  for (int o = 16; o; o >>= 1) m = fmaxf(m, __shfl_xor(m, o, 64));
  float e = __expf(s - m);
  float sum = e;
#pragma unroll
  for (int o = 16; o; o >>= 1) sum += __shfl_xor(sum, o, 64);
  wts[(size_t)t * 32 + p] = e / sum;
}

// -------- influence: out = a + wts @ protos; 16 tokens/block, fp32-exact --------
__global__ __launch_bounds__(256) void infl16(
    const bf16* __restrict__ ah, const bf16* __restrict__ al,
    const float* __restrict__ wts, const float* __restrict__ protos,
    bf16* __restrict__ oh, bf16* __restrict__ ol)
{
  int t0 = blockIdx.x * 16;
  int tid = threadIdx.x;
  __shared__ float wl[16][32];
  for (int i = tid; i < 512; i += 256)
    wl[i >> 5][i & 31] = wts[(size_t)(t0 + (i >> 5)) * 32 + (i & 31)];
  __syncthreads();
  int c0 = tid * 4;
  float acc[16][4];
#pragma unroll
  for (int tk = 0; tk < 16; tk++) {
    const bf16* rh = ah + (size_t)(t0 + tk) * H + c0;
    const bf16* rl = al + (size_t)(t0 + tk) * H + c0;
#pragma unroll
    for (int j = 0; j < 4; j++) acc[tk][j] = ldf(rh[j]) + ldf(rl[j]);
  }
  for (int p = 0; p < 32; p++) {
    float4 pv = *(const float4*)&protos[p * H + c0];
#pragma unroll
    for (int tk = 0; tk < 16; tk++) {
      float w = wl[tk][p];
      acc[tk][0] += w * pv.x; acc[tk][1] += w * pv.y;
      acc[tk][2] += w * pv.z; acc[tk][3] += w * pv.w;
    }
  }
#pragma unroll
  for (int tk = 0; tk < 16; tk++) {
    bf16* wh = oh + (size_t)(t0 + tk) * H + c0;
    bf16* wo = ol + (size_t)(t0 + tk) * H + c0;
#pragma unroll
    for (int j = 0; j < 4; j++) { bf16 h, lo; split2(acc[tk][j], h, lo); wh[j] = h; wo[j] = lo; }
  }
}

// -------- small-N GEMM (N=64): h2 = relu(A@W + b); A = bf16 pair, W fp32, out fp32 --------
__global__ __launch_bounds__(256) void gemm_small(
    const bf16* __restrict__ Ah, const bf16* __restrict__ Al,
    const float* __restrict__ W, const float* __restrict__ bias,
    float* __restrict__ C, int M, int N, int K)
{
  const int BK = 16;
  __shared__ float As[BK][64];
  __shared__ float Bs[BK][64];
  int tid = threadIdx.x;
  int tx = tid & 15, ty = tid >> 4;
  int bn0 = blockIdx.x * 64;
  int bm0 = blockIdx.y * 64;
  float acc[4][4] = {};
  int am = tid >> 2, ak = (tid & 3) * 4;
  int bk = tid >> 4, bn = (tid & 15) * 4;
  const bf16* Aph = Ah + (size_t)(bm0 + am) * K + ak;
  const bf16* Apl = Al + (size_t)(bm0 + am) * K + ak;
  const float* Wptr = W + (size_t)bk * N + bn0 + bn;
  for (int k0 = 0; k0 < K; k0 += BK) {
#pragma unroll
    for (int c = 0; c < 4; c++) As[ak + c][am] = ldf(Aph[c]) + ldf(Apl[c]);
#pragma unroll
    for (int c = 0; c < 4; c++) Bs[bk][bn + c] = Wptr[c];
    __syncthreads();
#pragma unroll
    for (int k = 0; k < BK; k++) {
      float a[4], b[4];
#pragma unroll
      for (int i = 0; i < 4; i++) a[i] = As[k][ty * 4 + i];
#pragma unroll
      for (int j = 0; j < 4; j++) b[j] = Bs[k][tx * 4 + j];
#pragma unroll
      for (int i = 0; i < 4; i++)
#pragma unroll
        for (int j = 0; j < 4; j++)
          acc[i][j] += a[i] * b[j];
    }
    __syncthreads();
    Aph += BK; Apl += BK;
    Wptr += (size_t)BK * N;
  }
#pragma unroll
  for (int i = 0; i < 4; i++) {
    float* Crow = C + (size_t)(bm0 + ty * 4 + i) * N + bn0;
#pragma unroll
    for (int j = 0; j < 4; j++) {
      int n = tx * 4 + j;
      Crow[n] = fmaxf(acc[i][j] + bias[bn0 + n], 0.f);
    }
  }
}

// ---------------- preds chunk: out[t0+t, c] = h2[t]@W3[:,c] + b3[c] (fp32) ----------------
__global__ __launch_bounds__(256) void FewShotABSALearner_46935402610855_kernel(
    const float* __restrict__ h2, const float* __restrict__ W3,
    const float* __restrict__ b3, float* __restrict__ out,
    int t0, int nElem, int out_size)
{
  int idx = blockIdx.x * 256 + threadIdx.x;
  if (idx >= nElem) return;
  int t = idx / 3, c = idx - t * 3;
  float acc = b3[c];
  const float* hr = h2 + (size_t)t * 64;
#pragma unroll
  for (int k = 0; k < 64; k++) acc += hr[k] * W3[k * 3 + c];
  int oi = t0 * 3 + idx;
  if (oi < out_size) out[oi] = acc;
}

extern "C" void kernel_launch(void* const* d_in, const int* in_sizes, int n_in,
                              void* d_out, int out_size, void* d_ws, size_t ws_size,
                              hipStream_t stream)
{
  (void)in_sizes; (void)n_in;
  const float* sup   = (const float*)d_in[0];
  const float* qry   = (const float*)d_in[1];
  const int*   lab   = (const int*)d_in[2];
  const float *aw_W1 = (const float*)d_in[3],  *aw_b1 = (const float*)d_in[4];
  const float *aw_W2 = (const float*)d_in[5],  *aw_b2 = (const float*)d_in[6];
  const float *aw_g  = (const float*)d_in[7],  *aw_be = (const float*)d_in[8];
  const float *ct_W1 = (const float*)d_in[9],  *ct_b1 = (const float*)d_in[10];
  const float *ct_W2 = (const float*)d_in[11], *ct_b2 = (const float*)d_in[12];
  const float *ct_g  = (const float*)d_in[13], *ct_be = (const float*)d_in[14];
  const float *ad_W1 = (const float*)d_in[15], *ad_b1 = (const float*)d_in[16];
  const float *ad_W2 = (const float*)d_in[17], *ad_b2 = (const float*)d_in[18];
  const float *cl_W1 = (const float*)d_in[19], *cl_b1 = (const float*)d_in[20];
  const float *cl_W2 = (const float*)d_in[21], *cl_b2 = (const float*)d_in[22];
  const float *cl_W3 = (const float*)d_in[23], *cl_b3 = (const float*)d_in[24];
  float* out = (float*)d_out;

  // ---- adaptive chunk size from ws_size (exact byte budgets) ----
  // fixed = 12x2MB sq-wts + clW1h 4MB [+ clW1l 4MB] + protos 128KB + pn pair 128KB
  // per-C = 6 act (C*2048 B) + union h2c|sims+wts (C*256 B) + rn (C*4 B) = 12548*C
  const size_t MB = 1 << 20;
  int C; bool clLo = true;
  if      (ws_size >= (size_t)239403008) C = 16384;
  else if (ws_size >= (size_t)136609792) C = 8192;
  else if (ws_size >= (size_t)85213184)  C = 4096;
  else if (ws_size >= (size_t)59514880)  C = 2048;
  else if (ws_size >= (size_t)46665728)  C = 1024;
  else { C = 1024; clLo = false; }
  const int Cs = (C < M_S) ? C : M_S;                 // support chunk
  const size_t actB = (size_t)C * H * sizeof(bf16);

  char* ws = (char*)d_ws;
  size_t off = 0;
  auto nxt = [&](size_t b) { char* p = ws + off; off += b; return p; };
  bf16* sqw[12];
  for (int i = 0; i < 12; i++) sqw[i] = (bf16*)nxt(2 * MB);
  bf16 *aw1h = sqw[0], *aw1l = sqw[1], *aw2h = sqw[2],  *aw2l = sqw[3];
  bf16 *ct1h = sqw[4], *ct1l = sqw[5], *ct2h = sqw[6],  *ct2l = sqw[7];
  bf16 *ad1h = sqw[8], *ad1l = sqw[9], *ad2h = sqw[10], *ad2l = sqw[11];
  bf16* clW1h = (bf16*)nxt(4 * MB);
  bf16* clW1l = clLo ? (bf16*)nxt(4 * MB) : nullptr;
  float* protos = (float*)nxt(NS * H * 4);
  bf16*  pnh    = (bf16*)nxt(NS * H * 2);
  bf16*  pnl    = (bf16*)nxt(NS * H * 2);
  char*  ub     = nxt((size_t)C * 256);               // union: h2c | sims+wts
  float* h2c   = (float*)ub;
  float* simsb = (float*)ub;
  float* wtsb  = (float*)(ub + (size_t)C * 128);
  float* rn    = (float*)nxt((size_t)C * 4);
  bf16 *R0h = (bf16*)nxt(actB), *R0l = (bf16*)nxt(actB);
  bf16 *R1h = (bf16*)nxt(actB), *R1l = (bf16*)nxt(actB);
  bf16 *R2h = (bf16*)nxt(actB), *R2l = (bf16*)nxt(actB);

  dim3 blk(256);
  dim3 blk2(512);
  dim3 tg(32, 32);
  dim3 ggq((C / 256) * 4);         // 1-D swizzled grid: nbm*4
  dim3 ggs((Cs / 256) * 4);

  // ---- weight prep: transpose + hi/lo split ----
  transpose_split<<<tg, blk, 0, stream>>>(aw_W1, aw1h, aw1l, H, H);
  transpose_split<<<tg, blk, 0, stream>>>(aw_W2, aw2h, aw2l, H, H);
  transpose_split<<<tg, blk, 0, stream>>>(ct_W1, ct1h, ct1l, H, H);
  transpose_split<<<tg, blk, 0, stream>>>(ct_W2, ct2h, ct2l, H, H);
  transpose_split<<<tg, blk, 0, stream>>>(ad_W1, ad1h, ad1l, H, H);
  transpose_split<<<tg, blk, 0, stream>>>(ad_W2, ad2h, ad2l, H, H);
  transpose_split<<<dim3(32, 64), blk, 0, stream>>>(cl_W1, clW1h, clW1l, 2 * H, H);

  // ---- support chunks -> prototypes ----
  for (int sc = 0; sc < M_S / Cs; sc++) {
    conv_split<<<(Cs * H) / 256, blk, 0, stream>>>(sup + (size_t)sc * Cs * H, R0h, R0l, Cs * H);
    gemm3p<true , true><<<ggs, blk2, 0, stream>>>(R0h, R0l, R0h, R0l, aw1h, aw1l, aw_b1, R1h, R1l, Cs, H, H, H);
    gemm3p<false, true><<<ggs, blk2, 0, stream>>>(R1h, R1l, R1h, R1l, aw2h, aw2l, aw_b2, R2h, R2l, Cs, H, H, H);
    ln_pair<<<Cs, blk, 0, stream>>>(R2h, R2l, aw_g, aw_be);
    proto_kernel<<<Cs / SS, blk, 0, stream>>>(R2h, R2l, lab + sc * Cs,
                                              protos + (size_t)sc * (Cs / SS) * H);
  }
  pn_kernel<<<NS, blk, 0, stream>>>(protos, pnh, pnl);

  // ---- query chunks ----
  for (int qc = 0; qc < T_Q / C; qc++) {
    const float* q0 = qry + (size_t)qc * C * H;
    conv_split<<<(C * H) / 256, blk, 0, stream>>>(q0, R2h, R2l, C * H);
    for (int it = 0; it < 5; it++) {
      rownorm_pair<<<C, blk, 0, stream>>>(R2h, R2l, rn);
      sims_mfma<<<C / 64, blk, 0, stream>>>(R2h, R2l, pnh, pnl, simsb);
      softmax32<<<C / 8, blk, 0, stream>>>(simsb, rn, wtsb);
      infl16<<<C / 16, blk, 0, stream>>>(R2h, R2l, wtsb, protos, R0h, R0l);
      gemm3p<true , true><<<ggq, blk2, 0, stream>>>(R0h, R0l, R0h, R0l, ad1h, ad1l, ad_b1, R1h, R1l, C, H, H, H);
      gemm3p<false, true><<<ggq, blk2, 0, stream>>>(R1h, R1l, R1h, R1l, ad2h, ad2l, ad_b2, R2h, R2l, C, H, H, H);
    }
    // aspect_aware head -> R1 = q_aw
    gemm3p<true , true><<<ggq, blk2, 0, stream>>>(R2h, R2l, R2h, R2l, aw1h, aw1l, aw_b1, R0h, R0l, C, H, H, H);
    gemm3p<false, true><<<ggq, blk2, 0, stream>>>(R0h, R0l, R0h, R0l, aw2h, aw2l, aw_b2, R1h, R1l, C, H, H, H);
    ln_pair<<<C, blk, 0, stream>>>(R1h, R1l, aw_g, aw_be);
    // contrastive head -> R2 = q_ct (adapted consumed)
    gemm3p<true , true><<<ggq, blk2, 0, stream>>>(R2h, R2l, R2h, R2l, ct1h, ct1l, ct_b1, R0h, R0l, C, H, H, H);
    gemm3p<false, true><<<ggq, blk2, 0, stream>>>(R0h, R0l, R0h, R0l, ct2h, ct2l, ct_b2, R2h, R2l, C, H, H, H);
    ln_pair<<<C, blk, 0, stream>>>(R2h, R2l, ct_g, ct_be);
    // classifier h1 = relu([q_aw | q_ct] @ cl_W1 + b1): two-pointer A, Ktot=2048
    if (clLo)
      gemm3p<true, true ><<<ggq, blk2, 0, stream>>>(R1h, R1l, R2h, R2l, clW1h, clW1l, cl_b1, R0h, R0l, C, H, H, 2 * H);
    else
      gemm3p<true, false><<<ggq, blk2, 0, stream>>>(R1h, R1l, R2h, R2l, clW1h, nullptr, cl_b1, R0h, R0l, C, H, H, 2 * H);
    // h2 = relu(h1 @ cl_W2 + b2)  [C x 64]
    gemm_small<<<dim3(1, C / 64), blk, 0, stream>>>(R0h, R0l, cl_W2, cl_b2, h2c, C, 64, H);
    // preds -> d_out
    FewShotABSALearner_46935402610855_kernel<<<(C * 3 + 255) / 256, blk, 0, stream>>>(
        h2c, cl_W3, cl_b3, out, qc * C, C * 3, out_size);
  }
}

// Round 9
// 2345.478 us; speedup vs baseline: 1.0600x; 1.0600x over previous
//
#include <hip/hip_runtime.h>
#include <hip/hip_bf16.h>

#define H 1024
#define NS 32
#define SS 256
#define T_Q 16384            /* query tokens  (64 x 256) */
#define M_S 8192             /* support tokens (32 x 256) */

typedef __hip_bfloat16 bf16;
typedef short short8 __attribute__((ext_vector_type(8)));
typedef float floatx4 __attribute__((ext_vector_type(4)));

__device__ __forceinline__ float ldf(const bf16& v) { return __bfloat162float(v); }

// two-term bf16 split: v ~= hi + lo  (residual ~2^-16 relative)
__device__ __forceinline__ void split2(float v, bf16& h, bf16& l) {
  h = __float2bfloat16(v);
  l = __float2bfloat16(v - __bfloat162float(h));
}

// async global->LDS, 16B per lane; LDS dest = wave-uniform base + lane*16
__device__ __forceinline__ void gl2lds16(const void* g, void* l) {
  __builtin_amdgcn_global_load_lds(
      (const __attribute__((address_space(1))) unsigned int*)g,
      (__attribute__((address_space(3))) unsigned int*)l, 16, 0, 0);
}

__device__ __forceinline__ short8 ld8s(const bf16* p) { return *(const short8*)p; }

__device__ __forceinline__ float bfbits2f(short s) {
  return __uint_as_float(((unsigned)(unsigned short)s) << 16);
}

// ---------------- fp32 -> bf16 hi/lo split convert ----------------
__global__ __launch_bounds__(256) void conv_split(const float* __restrict__ in,
                                                  bf16* __restrict__ oh,
                                                  bf16* __restrict__ ol, int n)
{
  int i = blockIdx.x * 256 + threadIdx.x;
  if (i < n) { bf16 h, l; split2(in[i], h, l); oh[i] = h; ol[i] = l; }
}

// -------- transpose + split: Wh/Wl[n][k] = split(W[k][n]).  grid (N/32, K/32) --------
__global__ __launch_bounds__(256) void transpose_split(
    const float* __restrict__ W, bf16* __restrict__ Wh, bf16* __restrict__ Wl,
    int K, int N)
{
  __shared__ float t[32][33];
  int n0 = blockIdx.x * 32, k0 = blockIdx.y * 32;
  int tx = threadIdx.x & 31, ty = threadIdx.x >> 5;
#pragma unroll
  for (int i = 0; i < 32; i += 8)
    t[ty + i][tx] = W[(size_t)(k0 + ty + i) * N + (n0 + tx)];
  __syncthreads();
#pragma unroll
  for (int i = 0; i < 32; i += 8) {
    bf16 h, l; split2(t[tx][ty + i], h, l);
    size_t o = (size_t)(n0 + ty + i) * K + (k0 + tx);
    Wh[o] = h;
    if (Wl) Wl[o] = l;
  }
}

// ---------------- split-bf16 MFMA GEMM, v6: read-ahead + minimal barriers ----------------
// (best verified GEMM: round-6, 2422 us total; reverted verbatim after the 32x32
// shape was disproven twice)
// C = act( [A0|A1] @ Wt^T + bias ), as Ah@Wh + Al@Wh (+ Ah@Wl).
// BM=256 BN=256 BK=32, 512 thr = 8 waves (2M x 4N), per-wave 128x64 out, 16x16x32 MFMA.
// Fragment-major LDS (per-lane SOURCE permutation, linear dest) -> 0 conflicts.
// Read-ahead A ping-pong (S0/S1); 2 barriers per K-step; counted gates:
// vmcnt(3) end-P2 (alpha(t+1) landed), vmcnt(0) in P3 (only beta outstanding).
template<bool RELU, bool HASWL>
__global__ __launch_bounds__(512, 2) void gemm3p(
    const bf16* __restrict__ A0h, const bf16* __restrict__ A0l,
    const bf16* __restrict__ A1h, const bf16* __restrict__ A1l,
    const bf16* __restrict__ Wh,  const bf16* __restrict__ Wl,
    const float* __restrict__ bias,
    bf16* __restrict__ Ch, bf16* __restrict__ Cl,
    int M, int N, int K0, int Ktot)
{
  (void)M;
  // per-buffer (32768 bf16 = 64KB): Ah[16 tiles]|Al[16]|Bh[16]|Bl[16], tile=512 bf16
  __shared__ __align__(16) bf16 lds[2 * 32768];   // 128 KB
  const int tid = threadIdx.x;
  const int w = tid >> 6, l = tid & 63;
  // bijective XCD swizzle: xcd pair -> one bn column panel
  const int nbm = gridDim.x >> 2;
  const int lid = blockIdx.x;
  const int xcd = lid & 7, ib = lid >> 3;
  const int half = nbm >> 1;
  const int bn = xcd >> 1;
  const int bm = (xcd & 1) * half + ib;
  const int wr = w >> 2, wn = w & 3;              // wave row 0..1, col 0..3
  const int m16 = l & 15, quad = l >> 4;
  const int srow = l & 15;                        // staging source row in tile
  const int scol = (l >> 4) * 8;                  // staging source k-offset
  const int la = l * 8;                           // lane's 16B slot (elems)

  floatx4 acc[8][4];
#pragma unroll
  for (int i = 0; i < 8; i++)
#pragma unroll
    for (int j = 0; j < 4; j++) { acc[i][j][0]=0.f; acc[i][j][1]=0.f; acc[i][j][2]=0.f; acc[i][j][3]=0.f; }

  // ---- staging assignment ----
  // alpha: B tiles {2w, 2w+1} h(+l)  +  one A load: tile {0,1,8,9}[w>>1], part w&1
  const size_t raB0 = (size_t)(bn * 256 + (2 * w)     * 16 + srow) * Ktot + scol;
  const size_t raB1 = (size_t)(bn * 256 + (2 * w + 1) * 16 + srow) * Ktot + scol;
  const int aT  = ((w >> 1) & 1) + ((w >> 1) >> 1) * 8;   // {0,1,8,9}
  const int aLo = w & 1;
  const size_t raA = (size_t)(bm * 256 + aT * 16 + srow) * H + scol;
  const int aDst = (aLo ? 8192 : 0) + aT * 512;
  // beta: 24 A loads over tiles {2..7,10..15} x {h,l}; wave w takes j = 3w..3w+2
  size_t raBt[3]; int bDst[3]; int bLo[3];
#pragma unroll
  for (int i = 0; i < 3; i++) {
    int j = w * 3 + i;
    int idx = j >> 1;
    int tb = (idx < 6) ? (idx + 2) : (idx + 4);           // {2..7,10..15}
    bLo[i] = j & 1;
    raBt[i] = (size_t)(bm * 256 + tb * 16 + srow) * H + scol;
    bDst[i] = (bLo[i] ? 8192 : 0) + tb * 512;
  }

  auto stage_alpha = [&](int t) {
    const int k0 = t << 5;
    const bf16 *Ah_, *Al_; int ke;
    if (k0 < K0) { Ah_ = A0h; Al_ = A0l; ke = k0; }
    else         { Ah_ = A1h; Al_ = A1l; ke = k0 - K0; }
    bf16* buf = lds + (t & 1) * 32768;
    gl2lds16(Wh + raB0 + k0, buf + 16384 + (2 * w) * 512);
    gl2lds16(Wh + raB1 + k0, buf + 16384 + (2 * w + 1) * 512);
    if (HASWL) {
      gl2lds16(Wl + raB0 + k0, buf + 24576 + (2 * w) * 512);
      gl2lds16(Wl + raB1 + k0, buf + 24576 + (2 * w + 1) * 512);
    }
    gl2lds16((aLo ? Al_ : Ah_) + raA + ke, buf + aDst);
  };
  auto stage_beta = [&](int t) {
    const int k0 = t << 5;
    const bf16 *Ah_, *Al_; int ke;
    if (k0 < K0) { Ah_ = A0h; Al_ = A0l; ke = k0; }
    else         { Ah_ = A1h; Al_ = A1l; ke = k0 - K0; }
    bf16* buf = lds + (t & 1) * 32768;
#pragma unroll
    for (int i = 0; i < 3; i++)
      gl2lds16((bLo[i] ? Al_ : Ah_) + raBt[i] + ke, buf + bDst[i]);
  };

  // prologue: stage step 0, drain (prologue only), pre-read step-0 P0 operands
  stage_alpha(0);
  stage_beta(0);
  asm volatile("s_waitcnt vmcnt(0)" ::: "memory");
  __builtin_amdgcn_s_barrier();

  short8 bh[4], bl8[4];                 // B frags of current step (all nt)
  short8 s0h[2], s0l[2], s1h[2], s1l[2]; // A mt-pair register ping-pong
  {
    const bf16* bB = lds + 16384 + wn * 2048 + la;
#pragma unroll
    for (int nt = 0; nt < 4; nt++) bh[nt] = ld8s(bB + nt * 512);
    if (HASWL) {
#pragma unroll
      for (int nt = 0; nt < 4; nt++) bl8[nt] = ld8s(bB + 8192 + nt * 512);
    }
    const bf16* bA = lds + wr * 4096 + la;
    s0h[0] = ld8s(bA);        s0h[1] = ld8s(bA + 512);
    s0l[0] = ld8s(bA + 8192); s0l[1] = ld8s(bA + 8704);
  }

  const int nT = Ktot >> 5;

#define MM3(MI, AH, AL)                                                                            \
    _Pragma("unroll")                                                                              \
    for (int nt = 0; nt < 4; nt++) {                                                               \
      acc[MI][nt] = __builtin_amdgcn_mfma_f32_16x16x32_bf16(AH, bh[nt],  acc[MI][nt], 0, 0, 0);    \
      acc[MI][nt] = __builtin_amdgcn_mfma_f32_16x16x32_bf16(AL, bh[nt],  acc[MI][nt], 0, 0, 0);    \
      if (HASWL)                                                                                   \
        acc[MI][nt] = __builtin_amdgcn_mfma_f32_16x16x32_bf16(AH, bl8[nt], acc[MI][nt], 0, 0, 0);  \
    }

  for (int t = 0; t < nT; ++t) {
    const bf16* buf  = lds + (t & 1) * 32768;
    const bf16* nbuf = lds + ((t + 1) & 1) * 32768;
    const bf16* bA   = buf + wr * 4096 + la;
    const bf16* bAl  = bA + 8192;

    // ---- P0: issue alpha(t+1); read A{2,3} -> S1; MFMA mt0,1 (S0) ----
    if (t + 1 < nT) stage_alpha(t + 1);
    s1h[0] = ld8s(bA + 1024);  s1h[1] = ld8s(bA + 1536);
    s1l[0] = ld8s(bAl + 1024); s1l[1] = ld8s(bAl + 1536);
    __builtin_amdgcn_s_setprio(1);
    MM3(0, s0h[0], s0l[0])
    MM3(1, s0h[1], s0l[1])
    __builtin_amdgcn_s_setprio(0);
    // (no barrier: buf is read-only this step)

    // ---- P1: issue beta(t+1); read A{4,5} -> S0; MFMA mt2,3 (S1) ----
    if (t + 1 < nT) stage_beta(t + 1);
    s0h[0] = ld8s(bA + 2048);  s0h[1] = ld8s(bA + 2560);
    s0l[0] = ld8s(bAl + 2048); s0l[1] = ld8s(bAl + 2560);
    __builtin_amdgcn_s_setprio(1);
    MM3(2, s1h[0], s1l[0])
    MM3(3, s1h[1], s1l[1])
    __builtin_amdgcn_s_setprio(0);
    // (no barrier)

    // ---- P2: read A{6,7} -> S1; MFMA mt4,5 (S0); gate alpha(t+1) ----
    s1h[0] = ld8s(bA + 3072);  s1h[1] = ld8s(bA + 3584);
    s1l[0] = ld8s(bAl + 3072); s1l[1] = ld8s(bAl + 3584);
    __builtin_amdgcn_s_setprio(1);
    MM3(4, s0h[0], s0l[0])
    MM3(5, s0h[1], s0l[1])
    __builtin_amdgcn_s_setprio(0);
    if (t + 1 < nT) asm volatile("s_waitcnt vmcnt(3)" ::: "memory");
    __builtin_amdgcn_s_barrier();

    // ---- P3: MFMA mt6,7 (S1); then read B(t+1)+A{0,1}(t+1) from nbuf; gate beta(t+1) ----
    __builtin_amdgcn_s_setprio(1);
    MM3(6, s1h[0], s1l[0])
    MM3(7, s1h[1], s1l[1])
    __builtin_amdgcn_s_setprio(0);
    if (t + 1 < nT) {
      const bf16* nbB = nbuf + 16384 + wn * 2048 + la;
      const bf16* nbA = nbuf + wr * 4096 + la;
#pragma unroll
      for (int nt = 0; nt < 4; nt++) bh[nt] = ld8s(nbB + nt * 512);
      if (HASWL) {
#pragma unroll
        for (int nt = 0; nt < 4; nt++) bl8[nt] = ld8s(nbB + 8192 + nt * 512);
      }
      s0h[0] = ld8s(nbA);        s0h[1] = ld8s(nbA + 512);
      s0l[0] = ld8s(nbA + 8192); s0l[1] = ld8s(nbA + 8704);
      asm volatile("s_waitcnt vmcnt(0)" ::: "memory");  // beta(t+1): only loads outstanding
    }
    __builtin_amdgcn_s_barrier();
  }
#undef MM3

  // epilogue: C/D layout col=lane&15, row=quad*4+reg
#pragma unroll
  for (int mt = 0; mt < 8; mt++) {
#pragma unroll
    for (int nt = 0; nt < 4; nt++) {
      int row0 = bm * 256 + wr * 128 + mt * 16 + quad * 4;
      int col  = bn * 256 + wn * 64 + nt * 16 + m16;
      float bv = bias ? bias[col] : 0.f;
#pragma unroll
      for (int r = 0; r < 4; r++) {
        float v = acc[mt][nt][r] + bv;
        if (RELU) v = fmaxf(v, 0.f);
        bf16 h, lo; split2(v, h, lo);
        size_t o = (size_t)(row0 + r) * N + col;
        Ch[o] = h; Cl[o] = lo;
      }
    }
  }
}

// ---------------- LayerNorm on hi/lo pair (fp32 stats), in place ----------------
__global__ __launch_bounds__(256) void ln_pair(
    bf16* __restrict__ hh, bf16* __restrict__ hl,
    const float* __restrict__ g, const float* __restrict__ be)
{
  int row = blockIdx.x;
  bf16* ph = hh + (size_t)row * H;
  bf16* pl = hl + (size_t)row * H;
  int tid = threadIdx.x;
  float v[4];
  float s = 0.f, sq = 0.f;
#pragma unroll
  for (int j = 0; j < 4; j++) {
    int hi = tid + 256 * j;
    v[j] = ldf(ph[hi]) + ldf(pl[hi]);
    s += v[j]; sq += v[j] * v[j];
  }
  __shared__ float rs[256], rq[256];
  rs[tid] = s; rq[tid] = sq; __syncthreads();
  for (int o = 128; o; o >>= 1) {
    if (tid < o) { rs[tid] += rs[tid + o]; rq[tid] += rq[tid + o]; }
    __syncthreads();
  }
  float mu   = rs[0] * (1.0f / H);
  float var  = rq[0] * (1.0f / H) - mu * mu;
  float rstd = rsqrtf(var + 1e-5f);
#pragma unroll
  for (int j = 0; j < 4; j++) {
    int hi = tid + 256 * j;
    bf16 h, l; split2(g[hi] * (v[j] - mu) * rstd + be[hi], h, l);
    ph[hi] = h; pl[hi] = l;
  }
}

// ------------- per-sentence masked-mean prototypes (pair in, fp32 out) -------------
__global__ __launch_bounds__(256) void proto_kernel(
    const bf16* __restrict__ eh, const bf16* __restrict__ el,
    const int* __restrict__ labels, float* __restrict__ protos_out)
{
  int p = blockIdx.x;
  int tid = threadIdx.x;
  __shared__ unsigned char lbl[SS];
  lbl[tid] = (labels[p * SS + tid] > 0) ? 1 : 0;
  __syncthreads();
  float acc[4] = {0.f, 0.f, 0.f, 0.f};
  int cnt = 0;
  const bf16* bh = eh + (size_t)p * SS * H;
  const bf16* bl = el + (size_t)p * SS * H;
  for (int s = 0; s < SS; s++) {
    if (lbl[s]) {
      cnt++;
      const bf16* rh = bh + (size_t)s * H;
      const bf16* rl = bl + (size_t)s * H;
#pragma unroll
      for (int j = 0; j < 4; j++)
        acc[j] += ldf(rh[tid + 256 * j]) + ldf(rl[tid + 256 * j]);
    }
  }
  float ic = 1.0f / fmaxf((float)cnt, 1.0f);
#pragma unroll
  for (int j = 0; j < 4; j++) protos_out[p * H + tid + 256 * j] = acc[j] * ic;
}

// ---------------- normalize prototypes -> pn bf16 hi/lo pair ----------------
__global__ __launch_bounds__(256) void pn_kernel(
    const float* __restrict__ protos, bf16* __restrict__ pnh, bf16* __restrict__ pnl)
{
  int p = blockIdx.x;
  int tid = threadIdx.x;
  __shared__ float red[256];
  float v[4];
  float sq = 0.f;
#pragma unroll
  for (int j = 0; j < 4; j++) { v[j] = protos[p * H + tid + 256 * j]; sq += v[j] * v[j]; }
  red[tid] = sq; __syncthreads();
  for (int o = 128; o; o >>= 1) {
    if (tid < o) red[tid] += red[tid + o];
    __syncthreads();
  }
  float inv = 1.0f / fmaxf(sqrtf(red[0]), 1e-8f);
#pragma unroll
  for (int j = 0; j < 4; j++) {
    bf16 h, l; split2(v[j] * inv, h, l);
    pnh[p * H + tid + 256 * j] = h;
    pnl[p * H + tid + 256 * j] = l;
  }
}

// ------- FUSED: rownorm + sims + softmax -> wts  (split-3 MFMA, N=32) -------
// M-tile 64, 4 waves (wave w owns rows w*16..w*16+15), K=1024, BK=32.
// Row sumsq rides the A-fragments already in registers: lane (quad,m16) of
// wave w holds row (w*16+m16), cols [k0+quad*8, k0+quad*8+8) each step ->
// per-lane partial sumsq; quad-axis reduce (shfl_xor 16,32) gives the row
// norm. Each output row's 32 sims live in one 16-lane group (x2 regs) ->
// softmax via shfl_xor 8,4,2,1. Writes wts directly; kills the separate
// rownorm_pair (full 64MB R2 re-read) and softmax32 dispatches.
// Numerics vs the 3-kernel path: max is exact; norm/denominator fp32
// summation order differs (~1e-7 rel) — negligible vs 4x absmax margin.
__global__ __launch_bounds__(256) void sims_fused(
    const bf16* __restrict__ Ah, const bf16* __restrict__ Al,
    const bf16* __restrict__ Bh, const bf16* __restrict__ Bl,
    float* __restrict__ wts)
{
  __shared__ bf16 AsH[64 * 32];
  __shared__ bf16 AsL[64 * 32];
  __shared__ bf16 BsH[32 * 32];
  __shared__ bf16 BsL[32 * 32];
  const int tid = threadIdx.x;
  const int w = tid >> 6, l = tid & 63;
  const int bm0 = blockIdx.x * 64;
  const int m16 = l & 15, quad = l >> 4;
  const int sr = l >> 2;           // staging row within wave segment
  const int sc = (l & 3) * 8;      // staging k-offset

  floatx4 acc[2];
#pragma unroll
  for (int nt = 0; nt < 2; nt++) { acc[nt][0]=0.f; acc[nt][1]=0.f; acc[nt][2]=0.f; acc[nt][3]=0.f; }
  float ss = 0.f;                  // partial sumsq of row (w*16+m16), k-lane quad

  for (int k0 = 0; k0 < H; k0 += 32) {
    gl2lds16(Ah + (size_t)(bm0 + w * 16 + sr) * H + k0 + sc, &AsH[w * 512]);
    gl2lds16(Al + (size_t)(bm0 + w * 16 + sr) * H + k0 + sc, &AsL[w * 512]);
    if (w < 2) gl2lds16(Bh + (size_t)(w * 16 + sr) * H + k0 + sc, &BsH[w * 512]);
    else       gl2lds16(Bl + (size_t)((w - 2) * 16 + sr) * H + k0 + sc, &BsL[(w - 2) * 512]);
    __syncthreads();

    short8 ah  = *(const short8*)&AsH[(w * 16 + m16) * 32 + quad * 8];
    short8 al8 = *(const short8*)&AsL[(w * 16 + m16) * 32 + quad * 8];
    // rownorm fused: ah/al8 are row (w*16+m16), cols k0+quad*8 .. +7
#pragma unroll
    for (int j = 0; j < 8; j++) {
      float v = bfbits2f(ah[j]) + bfbits2f(al8[j]);
      ss = fmaf(v, v, ss);
    }
#pragma unroll
    for (int nt = 0; nt < 2; nt++) {
      short8 bh  = *(const short8*)&BsH[(nt * 16 + m16) * 32 + quad * 8];
      short8 bl8 = *(const short8*)&BsL[(nt * 16 + m16) * 32 + quad * 8];
      acc[nt] = __builtin_amdgcn_mfma_f32_16x16x32_bf16(ah,  bh,  acc[nt], 0, 0, 0);
      acc[nt] = __builtin_amdgcn_mfma_f32_16x16x32_bf16(al8, bh,  acc[nt], 0, 0, 0);
      acc[nt] = __builtin_amdgcn_mfma_f32_16x16x32_bf16(ah,  bl8, acc[nt], 0, 0, 0);
    }
    __syncthreads();
  }

  // complete row (w*16+m16) sumsq: reduce over the quad axis (lanes l^16, l^32)
  ss += __shfl_xor(ss, 16, 64);
  ss += __shfl_xor(ss, 32, 64);
  float rnv = 1.0f / fmaxf(sqrtf(ss), 1e-8f);
  // redistribute: this lane's acc rows are quad*4+r; rn of row rr is held by
  // lanes with m16==rr (any quad) — pull from our own quad group.
  float rnr[4];
#pragma unroll
  for (int r = 0; r < 4; r++)
    rnr[r] = __shfl(rnv, (l & 48) + quad * 4 + r, 64);

  // softmax per acc row: 32 cols = 16 lanes (m16) x 2 regs (nt)
#pragma unroll
  for (int r = 0; r < 4; r++) {
    float s0 = acc[0][r] * rnr[r];
    float s1 = acc[1][r] * rnr[r];
    float m = fmaxf(s0, s1);
#pragma unroll
    for (int o = 8; o; o >>= 1) m = fmaxf(m, __shfl_xor(m, o, 64));
    float e0 = __expf(s0 - m), e1 = __expf(s1 - m);
    float sum = e0 + e1;
#pragma unroll
    for (int o = 8; o; o >>= 1) sum += __shfl_xor(sum, o, 64);
    int row = bm0 + w * 16 + quad * 4 + r;
    float inv = 1.0f / sum;
    wts[(size_t)row * 32 + m16]      = e0 * inv;
    wts[(size_t)row * 32 + 16 + m16] = e1 * inv;
  }
}

// -------- influence: out = a + wts @ protos; 16 tokens/block, fp32-exact --------
__global__ __launch_bounds__(256) void infl16(
    const bf16* __restrict__ ah, const bf16* __restrict__ al,
    const float* __restrict__ wts, const float* __restrict__ protos,
    bf16* __restrict__ oh, bf16* __restrict__ ol)
{
  int t0 = blockIdx.x * 16;
  int tid = threadIdx.x;
  __shared__ float wl[16][32];
  for (int i = tid; i < 512; i += 256)
    wl[i >> 5][i & 31] = wts[(size_t)(t0 + (i >> 5)) * 32 + (i & 31)];
  __syncthreads();
  int c0 = tid * 4;
  float acc[16][4];
#pragma unroll
  for (int tk = 0; tk < 16; tk++) {
    const bf16* rh = ah + (size_t)(t0 + tk) * H + c0;
    const bf16* rl = al + (size_t)(t0 + tk) * H + c0;
#pragma unroll
    for (int j = 0; j < 4; j++) acc[tk][j] = ldf(rh[j]) + ldf(rl[j]);
  }
  for (int p = 0; p < 32; p++) {
    float4 pv = *(const float4*)&protos[p * H + c0];
#pragma unroll
    for (int tk = 0; tk < 16; tk++) {
      float w = wl[tk][p];
      acc[tk][0] += w * pv.x; acc[tk][1] += w * pv.y;
      acc[tk][2] += w * pv.z; acc[tk][3] += w * pv.w;
    }
  }
#pragma unroll
  for (int tk = 0; tk < 16; tk++) {
    bf16* wh = oh + (size_t)(t0 + tk) * H + c0;
    bf16* wo = ol + (size_t)(t0 + tk) * H + c0;
#pragma unroll
    for (int j = 0; j < 4; j++) { bf16 h, lo; split2(acc[tk][j], h, lo); wh[j] = h; wo[j] = lo; }
  }
}

// -------- small-N GEMM (N=64): h2 = relu(A@W + b); A = bf16 pair, W fp32, out fp32 --------
__global__ __launch_bounds__(256) void gemm_small(
    const bf16* __restrict__ Ah, const bf16* __restrict__ Al,
    const float* __restrict__ W, const float* __restrict__ bias,
    float* __restrict__ C, int M, int N, int K)
{
  const int BK = 16;
  __shared__ float As[BK][64];
  __shared__ float Bs[BK][64];
  int tid = threadIdx.x;
  int tx = tid & 15, ty = tid >> 4;
  int bn0 = blockIdx.x * 64;
  int bm0 = blockIdx.y * 64;
  float acc[4][4] = {};
  int am = tid >> 2, ak = (tid & 3) * 4;
  int bk = tid >> 4, bn = (tid & 15) * 4;
  const bf16* Aph = Ah + (size_t)(bm0 + am) * K + ak;
  const bf16* Apl = Al + (size_t)(bm0 + am) * K + ak;
  const float* Wptr = W + (size_t)bk * N + bn0 + bn;
  for (int k0 = 0; k0 < K; k0 += BK) {
#pragma unroll
    for (int c = 0; c < 4; c++) As[ak + c][am] = ldf(Aph[c]) + ldf(Apl[c]);
#pragma unroll
    for (int c = 0; c < 4; c++) Bs[bk][bn + c] = Wptr[c];
    __syncthreads();
#pragma unroll
    for (int k = 0; k < BK; k++) {
      float a[4], b[4];
#pragma unroll
      for (int i = 0; i < 4; i++) a[i] = As[k][ty * 4 + i];
#pragma unroll
      for (int j = 0; j < 4; j++) b[j] = Bs[k][tx * 4 + j];
#pragma unroll
      for (int i = 0; i < 4; i++)
#pragma unroll
        for (int j = 0; j < 4; j++)
          acc[i][j] += a[i] * b[j];
    }
    __syncthreads();
    Aph += BK; Apl += BK;
    Wptr += (size_t)BK * N;
  }
#pragma unroll
  for (int i = 0; i < 4; i++) {
    float* Crow = C + (size_t)(bm0 + ty * 4 + i) * N + bn0;
#pragma unroll
    for (int j = 0; j < 4; j++) {
      int n = tx * 4 + j;
      Crow[n] = fmaxf(acc[i][j] + bias[bn0 + n], 0.f);
    }
  }
}

// ---------------- preds chunk: out[t0+t, c] = h2[t]@W3[:,c] + b3[c] (fp32) ----------------
__global__ __launch_bounds__(256) void FewShotABSALearner_46935402610855_kernel(
    const float* __restrict__ h2, const float* __restrict__ W3,
    const float* __restrict__ b3, float* __restrict__ out,
    int t0, int nElem, int out_size)
{
  int idx = blockIdx.x * 256 + threadIdx.x;
  if (idx >= nElem) return;
  int t = idx / 3, c = idx - t * 3;
  float acc = b3[c];
  const float* hr = h2 + (size_t)t * 64;
#pragma unroll
  for (int k = 0; k < 64; k++) acc += hr[k] * W3[k * 3 + c];
  int oi = t0 * 3 + idx;
  if (oi < out_size) out[oi] = acc;
}

extern "C" void kernel_launch(void* const* d_in, const int* in_sizes, int n_in,
                              void* d_out, int out_size, void* d_ws, size_t ws_size,
                              hipStream_t stream)
{
  (void)in_sizes; (void)n_in;
  const float* sup   = (const float*)d_in[0];
  const float* qry   = (const float*)d_in[1];
  const int*   lab   = (const int*)d_in[2];
  const float *aw_W1 = (const float*)d_in[3],  *aw_b1 = (const float*)d_in[4];
  const float *aw_W2 = (const float*)d_in[5],  *aw_b2 = (const float*)d_in[6];
  const float *aw_g  = (const float*)d_in[7],  *aw_be = (const float*)d_in[8];
  const float *ct_W1 = (const float*)d_in[9],  *ct_b1 = (const float*)d_in[10];
  const float *ct_W2 = (const float*)d_in[11], *ct_b2 = (const float*)d_in[12];
  const float *ct_g  = (const float*)d_in[13], *ct_be = (const float*)d_in[14];
  const float *ad_W1 = (const float*)d_in[15], *ad_b1 = (const float*)d_in[16];
  const float *ad_W2 = (const float*)d_in[17], *ad_b2 = (const float*)d_in[18];
  const float *cl_W1 = (const float*)d_in[19], *cl_b1 = (const float*)d_in[20];
  const float *cl_W2 = (const float*)d_in[21], *cl_b2 = (const float*)d_in[22];
  const float *cl_W3 = (const float*)d_in[23], *cl_b3 = (const float*)d_in[24];
  float* out = (float*)d_out;

  // ---- adaptive chunk size from ws_size (exact byte budgets) ----
  // fixed = 12x2MB sq-wts + clW1h 4MB [+ clW1l 4MB] + protos 128KB + pn pair 128KB
  // per-C = 6 act (C*2048 B) + union h2c|sims+wts (C*256 B) + rn (C*4 B) = 12548*C
  const size_t MB = 1 << 20;
  int C; bool clLo = true;
  if      (ws_size >= (size_t)239403008) C = 16384;
  else if (ws_size >= (size_t)136609792) C = 8192;
  else if (ws_size >= (size_t)85213184)  C = 4096;
  else if (ws_size >= (size_t)59514880)  C = 2048;
  else if (ws_size >= (size_t)46665728)  C = 1024;
  else { C = 1024; clLo = false; }
  const int Cs = (C < M_S) ? C : M_S;                 // support chunk
  const size_t actB = (size_t)C * H * sizeof(bf16);

  char* ws = (char*)d_ws;
  size_t off = 0;
  auto nxt = [&](size_t b) { char* p = ws + off; off += b; return p; };
  bf16* sqw[12];
  for (int i = 0; i < 12; i++) sqw[i] = (bf16*)nxt(2 * MB);
  bf16 *aw1h = sqw[0], *aw1l = sqw[1], *aw2h = sqw[2],  *aw2l = sqw[3];
  bf16 *ct1h = sqw[4], *ct1l = sqw[5], *ct2h = sqw[6],  *ct2l = sqw[7];
  bf16 *ad1h = sqw[8], *ad1l = sqw[9], *ad2h = sqw[10], *ad2l = sqw[11];
  bf16* clW1h = (bf16*)nxt(4 * MB);
  bf16* clW1l = clLo ? (bf16*)nxt(4 * MB) : nullptr;
  float* protos = (float*)nxt(NS * H * 4);
  bf16*  pnh    = (bf16*)nxt(NS * H * 2);
  bf16*  pnl    = (bf16*)nxt(NS * H * 2);
  char*  ub     = nxt((size_t)C * 256);               // union: h2c | wts
  float* h2c   = (float*)ub;
  float* wtsb  = (float*)(ub + (size_t)C * 128);
  float* rn    = (float*)nxt((size_t)C * 4);
  (void)rn;                                           // fused into sims_fused
  bf16 *R0h = (bf16*)nxt(actB), *R0l = (bf16*)nxt(actB);
  bf16 *R1h = (bf16*)nxt(actB), *R1l = (bf16*)nxt(actB);
  bf16 *R2h = (bf16*)nxt(actB), *R2l = (bf16*)nxt(actB);

  dim3 blk(256);
  dim3 blk2(512);
  dim3 tg(32, 32);
  dim3 ggq((C / 256) * 4);         // 1-D swizzled grid: nbm*4
  dim3 ggs((Cs / 256) * 4);

  // ---- weight prep: transpose + hi/lo split ----
  transpose_split<<<tg, blk, 0, stream>>>(aw_W1, aw1h, aw1l, H, H);
  transpose_split<<<tg, blk, 0, stream>>>(aw_W2, aw2h, aw2l, H, H);
  transpose_split<<<tg, blk, 0, stream>>>(ct_W1, ct1h, ct1l, H, H);
  transpose_split<<<tg, blk, 0, stream>>>(ct_W2, ct2h, ct2l, H, H);
  transpose_split<<<tg, blk, 0, stream>>>(ad_W1, ad1h, ad1l, H, H);
  transpose_split<<<tg, blk, 0, stream>>>(ad_W2, ad2h, ad2l, H, H);
  transpose_split<<<dim3(32, 64), blk, 0, stream>>>(cl_W1, clW1h, clW1l, 2 * H, H);

  // ---- support chunks -> prototypes ----
  for (int sc = 0; sc < M_S / Cs; sc++) {
    conv_split<<<(Cs * H) / 256, blk, 0, stream>>>(sup + (size_t)sc * Cs * H, R0h, R0l, Cs * H);
    gemm3p<true , true><<<ggs, blk2, 0, stream>>>(R0h, R0l, R0h, R0l, aw1h, aw1l, aw_b1, R1h, R1l, Cs, H, H, H);
    gemm3p<false, true><<<ggs, blk2, 0, stream>>>(R1h, R1l, R1h, R1l, aw2h, aw2l, aw_b2, R2h, R2l, Cs, H, H, H);
    ln_pair<<<Cs, blk, 0, stream>>>(R2h, R2l, aw_g, aw_be);
    proto_kernel<<<Cs / SS, blk, 0, stream>>>(R2h, R2l, lab + sc * Cs,
                                              protos + (size_t)sc * (Cs / SS) * H);
  }
  pn_kernel<<<NS, blk, 0, stream>>>(protos, pnh, pnl);

  // ---- query chunks ----
  for (int qc = 0; qc < T_Q / C; qc++) {
    const float* q0 = qry + (size_t)qc * C * H;
    conv_split<<<(C * H) / 256, blk, 0, stream>>>(q0, R2h, R2l, C * H);
    for (int it = 0; it < 5; it++) {
      sims_fused<<<C / 64, blk, 0, stream>>>(R2h, R2l, pnh, pnl, wtsb);
      infl16<<<C / 16, blk, 0, stream>>>(R2h, R2l, wtsb, protos, R0h, R0l);
      gemm3p<true , true><<<ggq, blk2, 0, stream>>>(R0h, R0l, R0h, R0l, ad1h, ad1l, ad_b1, R1h, R1l, C, H, H, H);
      gemm3p<false, true><<<ggq, blk2, 0, stream>>>(R1h, R1l, R1h, R1l, ad2h, ad2l, ad_b2, R2h, R2l, C, H, H, H);
    }
    // aspect_aware head -> R1 = q_aw
    gemm3p<true , true><<<ggq, blk2, 0, stream>>>(R2h, R2l, R2h, R2l, aw1h, aw1l, aw_b1, R0h, R0l, C, H, H, H);
    gemm3p<false, true><<<ggq, blk2, 0, stream>>>(R0h, R0l, R0h, R0l, aw2h, aw2l, aw_b2, R1h, R1l, C, H, H, H);
    ln_pair<<<C, blk, 0, stream>>>(R1h, R1l, aw_g, aw_be);
    // contrastive head -> R2 = q_ct (adapted consumed)
    gemm3p<true , true><<<ggq, blk2, 0, stream>>>(R2h, R2l, R2h, R2l, ct1h, ct1l, ct_b1, R0h, R0l, C, H, H, H);
    gemm3p<false, true><<<ggq, blk2, 0, stream>>>(R0h, R0l, R0h, R0l, ct2h, ct2l, ct_b2, R2h, R2l, C, H, H, H);
    ln_pair<<<C, blk, 0, stream>>>(R2h, R2l, ct_g, ct_be);
    // classifier h1 = relu([q_aw | q_ct] @ cl_W1 + b1): two-pointer A, Ktot=2048
    if (clLo)
      gemm3p<true, true ><<<ggq, blk2, 0, stream>>>(R1h, R1l, R2h, R2l, clW1h, clW1l, cl_b1, R0h, R0l, C, H, H, 2 * H);
    else
      gemm3p<true, false><<<ggq, blk2, 0, stream>>>(R1h, R1l, R2h, R2l, clW1h, nullptr, cl_b1, R0h, R0l, C, H, H, 2 * H);
    // h2 = relu(h1 @ cl_W2 + b2)  [C x 64]
    gemm_small<<<dim3(1, C / 64), blk, 0, stream>>>(R0h, R0l, cl_W2, cl_b2, h2c, C, 64, H);
    // preds -> d_out
    FewShotABSALearner_46935402610855_kernel<<<(C * 3 + 255) / 256, blk, 0, stream>>>(
        h2c, cl_W3, cl_b3, out, qc * C, C * 3, out_size);
  }
}